// Round 9
// baseline (1211.405 us; speedup 1.0000x reference)
//
#include <hip/hip_runtime.h>

typedef __attribute__((ext_vector_type(8))) _Float16 f16x8;
typedef __attribute__((ext_vector_type(4))) _Float16 f16x4;
typedef __attribute__((ext_vector_type(4))) float f32x4;

// ---------------------------------------------------------------------------
// mask_make: m = (mask_p < 0.1); x0 = fp16 blocked [b][pix][32] of x*mask;
// fused block-aggregated active-site compaction (1 global atomic / block).
// ---------------------------------------------------------------------------
__global__ void mask_make(const float* __restrict__ x, const float* __restrict__ mp,
                          float* __restrict__ m, _Float16* __restrict__ x0,
                          int* __restrict__ act, int* __restrict__ cnt,
                          int B, int HW) {
    int i = blockIdx.x * blockDim.x + threadIdx.x;
    const int tid = threadIdx.x;
    const int lane = tid & 63;
    const int wv = tid >> 6;
    bool active = (mp[i] < 0.1f);
    float mv = active ? 1.0f : 0.0f;
    m[i] = mv;
    int b = i / HW, p = i - b * HW;           // b uniform per block (HW % 256 == 0)
    const float* xb = x + ((size_t)b * 32) * HW + p;
    _Float16* ob = x0 + (size_t)i * 32;
    #pragma unroll
    for (int c = 0; c < 32; ++c) ob[c] = (_Float16)(xb[(size_t)c * HW] * mv);

    __shared__ int wcnt[4];
    __shared__ int bbase;
    unsigned long long ball = __ballot(active);
    int wtot = __popcll(ball);
    int prefix = __popcll(ball & ((1ull << lane) - 1ull));
    if (lane == 0) wcnt[wv] = wtot;
    __syncthreads();
    if (tid == 0) {
        int s = 0;
        #pragma unroll
        for (int w = 0; w < 4; ++w) { int tv = wcnt[w]; wcnt[w] = s; s += tv; }
        bbase = (s > 0) ? atomicAdd(&cnt[b], s) : 0;
    }
    __syncthreads();
    if (active) act[b * HW + bbase + wcnt[wv] + prefix] = p;
}

// 3x3 stride-2 pad-1 max-pool on (B,1,H,W) mask
__global__ void mask_down(const float* __restrict__ mi, float* __restrict__ mo,
                          int B, int Hi, int Wi, int Ho, int Wo) {
    int i = blockIdx.x * blockDim.x + threadIdx.x;
    if (i >= B * Ho * Wo) return;
    int wo = i % Wo;
    int t = i / Wo;
    int ho = t % Ho;
    int b = t / Ho;
    float v = 0.0f;
    #pragma unroll
    for (int kh = 0; kh < 3; ++kh) {
        int hi = ho * 2 + kh - 1;
        if (hi < 0 || hi >= Hi) continue;
        #pragma unroll
        for (int kw = 0; kw < 3; ++kw) {
            int wi = wo * 2 + kw - 1;
            if (wi < 0 || wi >= Wi) continue;
            v = fmaxf(v, mi[((size_t)b * Hi + hi) * Wi + wi]);
        }
    }
    mo[i] = v;
}

// ---------------------------------------------------------------------------
// Fused weight reorder: all 23 tensors, fp32 OIHW -> fp16 [chunk][co][CK]
// ---------------------------------------------------------------------------
struct WSeg { const float* src; int cin, cout, ck, cum; };
struct WArgs { WSeg seg[23]; int total; };

__global__ void reorder_all(WArgs A, _Float16* __restrict__ rw) {
    int idx = blockIdx.x * 256 + threadIdx.x;
    if (idx >= A.total) return;
    int s = 0;
    #pragma unroll
    for (int k = 1; k < 23; ++k) if (idx >= A.seg[k].cum) s = k;
    WSeg g = A.seg[s];
    int local = idx - g.cum;
    int kk = local % g.ck;
    int t2 = local / g.ck;
    int co = t2 % g.cout;
    int chunk = t2 / g.cout;
    int chunkc = g.cin / g.ck;
    int tap = chunk / chunkc, cc = chunk - tap * chunkc;
    int ci = cc * g.ck + kk;
    rw[g.cum + local] = (_Float16)g.src[((size_t)co * g.cin + ci) * 9 + tap];
}

// ---------------------------------------------------------------------------
// Dense implicit-GEMM conv3x3 (pad1, stride 1/2), fp16 MFMA, fp32 accum.
// BM=64, BN pixels/block, K chunked by CK tap-major. Depth-2 global prefetch
// with named vA/vB reg buffers; weight regs double-buffered awA/awB.
// ---------------------------------------------------------------------------
template<int BM, int BN, int CK>
__global__ __launch_bounds__(256, 4)
void conv_mfma(const _Float16* __restrict__ in, const _Float16* __restrict__ rw,
               const float* __restrict__ s, const float* __restrict__ t,
               const float* __restrict__ mask, const _Float16* __restrict__ res,
               float* __restrict__ out32, _Float16* __restrict__ out16,
               int Cin, int Cout, int Hin, int Win, int Hout, int Wout,
               int TH, int TW, int stride, int relu)
{
    constexpr int WM = BM / 2;
    constexpr int WAVES_N = 2;
    constexpr int WN = BN / WAVES_N;
    constexpr int MR = WM / 16;
    constexpr int NR = WN / 16;
    constexpr int KH = CK / 32;
    constexpr int ELEMS = (CK * BN) / 256;   // halves per thread per chunk
    constexpr int NV = ELEMS / 8;
    constexpr int TPP = 256 / BN;            // threads per pixel
    constexpr int LDST = CK + 8;

    __shared__ _Float16 Bsm[2][BN * LDST];

    const int tid = threadIdx.x;
    const int lane = tid & 63;
    const int wv = tid >> 6;
    const int wm = wv >> 1;
    const int wn = wv & 1;
    const int row = lane & 15, q = lane >> 4;

    const int tilesX = Wout / TW;
    const int oy0 = (blockIdx.x / tilesX) * TH;
    const int ox0 = (blockIdx.x % tilesX) * TW;
    const int co0 = blockIdx.y * BM;
    const int b = blockIdx.z;

    const int HWin = Hin * Win;
    const int HWo = Hout * Wout;
    const int cicn = Cin >> 5;
    const int cocn = Cout >> 5;
    const int chunkc = Cin / CK;
    const int nIter = 9 * chunkc;

    // staging: TPP threads cover one pixel's CK halves
    const int sn = tid / TPP;
    const int kb = (tid % TPP) * ELEMS;
    const int sty = sn / TW;
    const int stx = sn - sty * TW;
    const int soy = oy0 + sty;
    const int sox = ox0 + stx;

    f32x4 acc[MR][NR];
    #pragma unroll
    for (int m = 0; m < MR; ++m)
        #pragma unroll
        for (int n = 0; n < NR; ++n)
            #pragma unroll
            for (int r = 0; r < 4; ++r) acc[m][n][r] = 0.0f;

    auto LOADG = [&](int c, f16x8* dst) {
        int tap = c / chunkc, cc = c - tap * chunkc;
        int iy = soy * stride + (tap / 3) - 1;
        int ix = sox * stride + (tap - (tap / 3) * 3) - 1;
        bool ok = (iy >= 0 && iy < Hin && ix >= 0 && ix < Win);
        size_t pixoff = (size_t)iy * Win + ix;
        #pragma unroll
        for (int i = 0; i < NV; ++i) {
            int k = kb + 8 * i;
            const _Float16* p = in +
                (((size_t)(b * cicn + cc * KH + (k >> 5)) * HWin + pixoff) << 5) + (k & 31);
            dst[i] = ok ? *(const f16x8*)p : f16x8{};
        }
    };
    auto LOADW = [&](int c, f16x8 (&dst)[KH][MR]) {
        #pragma unroll
        for (int m = 0; m < MR; ++m) {
            int co = co0 + wm * WM + m * 16 + row;
            const _Float16* ap = rw + ((size_t)c * Cout + co) * CK + (q << 3);
            #pragma unroll
            for (int h = 0; h < KH; ++h) dst[h][m] = *(const f16x8*)(ap + 32 * h);
        }
    };
    auto WLDS = [&](int buf, const f16x8* v) {
        #pragma unroll
        for (int i = 0; i < NV; ++i)
            *(f16x8*)&Bsm[buf][sn * LDST + kb + 8 * i] = v[i];
    };
    auto DO_CHUNK = [&](const _Float16* bp, f16x8 (&awx)[KH][MR]) {
        f16x8 bh[KH][NR];
        #pragma unroll
        for (int n = 0; n < NR; ++n) {
            int nl = wn * WN + n * 16 + row;
            const _Float16* bb = bp + nl * LDST + (q << 3);
            #pragma unroll
            for (int h = 0; h < KH; ++h) bh[h][n] = *(const f16x8*)(bb + 32 * h);
        }
        #pragma unroll
        for (int h = 0; h < KH; ++h)
            #pragma unroll
            for (int m = 0; m < MR; ++m)
                #pragma unroll
                for (int n = 0; n < NR; ++n)
                    acc[m][n] = __builtin_amdgcn_mfma_f32_16x16x32_f16(awx[h][m], bh[h][n], acc[m][n], 0, 0, 0);
    };

    f16x8 awA[KH][MR], awB[KH][MR];
    f16x8 vA[NV], vB[NV];
    LOADG(0, vA);
    LOADW(0, awA);
    WLDS(0, vA);
    if (1 < nIter) { LOADG(1, vB); LOADW(1, awB); }
    __syncthreads();

    for (int c = 0; c < nIter; c += 2) {
        // even chunk c: Bsm[0], awA
        bool n1 = (c + 1) < nIter, n2 = (c + 2) < nIter, n3 = (c + 3) < nIter;
        if (n2) LOADG(c + 2, vA);
        DO_CHUNK(&Bsm[0][0], awA);
        if (n2) LOADW(c + 2, awA);
        if (n1) WLDS(1, vB);
        __syncthreads();
        if (!n1) break;
        // odd chunk c+1: Bsm[1], awB
        if (n3) LOADG(c + 3, vB);
        DO_CHUNK(&Bsm[1][0], awB);
        if (n3) LOADW(c + 3, awB);
        if (n2) WLDS(0, vA);
        __syncthreads();
    }

    int pix[NR]; float mv[NR];
    #pragma unroll
    for (int n = 0; n < NR; ++n) {
        int nl = wn * WN + n * 16 + row;
        int ty = nl / TW, tx = nl - ty * TW;
        pix[n] = (oy0 + ty) * Wout + (ox0 + tx);
        mv[n] = mask ? mask[(size_t)b * HWo + pix[n]] : 1.0f;
    }
    #pragma unroll
    for (int m = 0; m < MR; ++m) {
        int cb = co0 + wm * WM + m * 16 + q * 4;
        float sc[4], sh[4];
        #pragma unroll
        for (int r = 0; r < 4; ++r) { sc[r] = s[cb + r]; sh[r] = t[cb + r]; }
        #pragma unroll
        for (int n = 0; n < NR; ++n) {
            size_t boff = ((size_t)(b * cocn + (cb >> 5)) * HWo + pix[n]) * 32 + (cb & 31);
            float val[4];
            #pragma unroll
            for (int r = 0; r < 4; ++r) val[r] = (acc[m][n][r] * sc[r] + sh[r]) * mv[n];
            if (res) {
                f16x4 rv = *(const f16x4*)&res[boff];
                #pragma unroll
                for (int r = 0; r < 4; ++r) val[r] += (float)rv[r];
            }
            if (relu) {
                #pragma unroll
                for (int r = 0; r < 4; ++r) val[r] = fmaxf(val[r], 0.0f);
            }
            if (out16) {
                f16x4 pk;
                #pragma unroll
                for (int r = 0; r < 4; ++r) pk[r] = (_Float16)val[r];
                *(f16x4*)&out16[boff] = pk;
            }
            if (out32) {
                #pragma unroll
                for (int r = 0; r < 4; ++r)
                    out32[((size_t)b * Cout + cb + r) * HWo + pix[n]] = val[r];
            }
        }
    }
}

// ---------------------------------------------------------------------------
// Sparse stage-1 conv, barrier-free: Cin=Cout=32 gathered over active list.
// ---------------------------------------------------------------------------
__global__ __launch_bounds__(256, 4)
void conv_sparse(const _Float16* __restrict__ in, const _Float16* __restrict__ rw,
                 const float* __restrict__ s, const float* __restrict__ t,
                 const int* __restrict__ act, const int* __restrict__ cnt,
                 const _Float16* __restrict__ res,
                 float* __restrict__ out32, _Float16* __restrict__ out16,
                 int Hin, int Win, int relu)
{
    const int tid = threadIdx.x;
    const int lane = tid & 63;
    const int wv = tid >> 6;
    const int row = lane & 15, q = lane >> 4;
    const int b = blockIdx.z;
    const int HW = Hin * Win;
    const int nb = cnt[b];
    const int base = (blockIdx.x * 4 + wv) * 16;
    if (base >= nb) return;

    const int* actb = act + b * HW;
    const _Float16* inb = in + ((size_t)b * HW << 5);

    int j = base + row;
    bool vn = j < nb;
    int pn = vn ? actb[j] : 0;
    int py = pn / Win, px = pn - py * Win;

    f32x4 acc0, acc1;
    #pragma unroll
    for (int r = 0; r < 4; ++r) { acc0[r] = 0.0f; acc1[r] = 0.0f; }

    #pragma unroll
    for (int c = 0; c < 9; ++c) {
        const int dy = c / 3 - 1, dx = c - (c / 3) * 3 - 1;
        f16x8 a0 = *(const f16x8*)(rw + ((size_t)c * 32 + row) * 32 + (q << 3));
        f16x8 a1 = *(const f16x8*)(rw + ((size_t)c * 32 + 16 + row) * 32 + (q << 3));
        int iy = py + dy, ix = px + dx;
        bool ok = vn && iy >= 0 && iy < Hin && ix >= 0 && ix < Win;
        f16x8 bf = ok ? *(const f16x8*)(inb + ((size_t)(iy * Win + ix) << 5) + (q << 3))
                      : f16x8{};
        acc0 = __builtin_amdgcn_mfma_f32_16x16x32_f16(a0, bf, acc0, 0, 0, 0);
        acc1 = __builtin_amdgcn_mfma_f32_16x16x32_f16(a1, bf, acc1, 0, 0, 0);
    }

    if (!vn) return;
    size_t pbase = ((size_t)b * HW + pn) << 5;
    #pragma unroll
    for (int m = 0; m < 2; ++m) {
        const f32x4& am = m ? acc1 : acc0;
        int cb = m * 16 + q * 4;
        float val[4];
        #pragma unroll
        for (int r = 0; r < 4; ++r) val[r] = am[r] * s[cb + r] + t[cb + r];
        if (res) {
            f16x4 rv = *(const f16x4*)&res[pbase + cb];
            #pragma unroll
            for (int r = 0; r < 4; ++r) val[r] += (float)rv[r];
        }
        if (relu) {
            #pragma unroll
            for (int r = 0; r < 4; ++r) val[r] = fmaxf(val[r], 0.0f);
        }
        f16x4 pk;
        #pragma unroll
        for (int r = 0; r < 4; ++r) pk[r] = (_Float16)val[r];
        *(f16x4*)&out16[pbase + cb] = pk;
        if (out32) {
            #pragma unroll
            for (int r = 0; r < 4; ++r)
                out32[((size_t)(b * 32 + cb + r)) * HW + pn] = val[r];
        }
    }
}

extern "C" void kernel_launch(void* const* d_in, const int* in_sizes, int n_in,
                              void* d_out, int out_size, void* d_ws, size_t ws_size,
                              hipStream_t stream) {
    const int B = 2;

    const float* x      = (const float*)d_in[0];
    const float* mask_p = (const float*)d_in[1];
    const float* w1  = (const float*)d_in[2];
    const float* s1  = (const float*)d_in[3];
    const float* t1  = (const float*)d_in[4];
    const float* wd2 = (const float*)d_in[5];
    const float* w2  = (const float*)d_in[6];
    const float* s2  = (const float*)d_in[7];
    const float* t2  = (const float*)d_in[8];
    const float* wd3 = (const float*)d_in[9];
    const float* w3  = (const float*)d_in[10];
    const float* s3  = (const float*)d_in[11];
    const float* t3  = (const float*)d_in[12];
    const float* wd4 = (const float*)d_in[13];
    const float* w4  = (const float*)d_in[14];
    const float* s4  = (const float*)d_in[15];
    const float* t4  = (const float*)d_in[16];
    const float* w5  = (const float*)d_in[17];
    const float* s5  = (const float*)d_in[18];
    const float* t5  = (const float*)d_in[19];

    // d_out slices (fp32 NCHW)
    float* x1o = (float*)d_out;
    float* x2o = x1o + 16777216;
    float* x3o = x2o + 8388608;
    float* x4o = x3o + 4194304;
    float* x5o = x4o + 2097152;

    // workspace
    _Float16* rwbase = (_Float16*)d_ws;        // 5,299,200 halves
    float* m1 = (float*)d_ws + 2649600;
    float* m2 = m1 + 524288;
    float* m3 = m2 + 131072;
    float* m4 = m3 + 32768;
    int* act  = (int*)(m4 + 8192);             // 524288 ints
    int* cnt  = act + 524288;                  // 2 ints (+pad)
    _Float16* P = (_Float16*)(cnt + 32);
    _Float16* Q = P + 16777216;
    _Float16* R = Q + 16777216;

    // ---- fused weight reorder (1 launch) ----
    WArgs wa;
    int cum = 0, si = 0;
    const _Float16* rp[23];
    auto addseg = [&](const float* src, int cin, int cout, int ck) {
        wa.seg[si].src = src; wa.seg[si].cin = cin; wa.seg[si].cout = cout;
        wa.seg[si].ck = ck; wa.seg[si].cum = cum;
        rp[si] = rwbase + cum;
        cum += cout * cin * 9; si++;
    };
    for (int i = 0; i < 5; ++i) addseg(w1 + (size_t)i * 9216, 32, 32, 32);
    addseg(wd2, 32, 64, 32);
    for (int i = 0; i < 4; ++i) addseg(w2 + (size_t)i * 36864, 64, 64, 64);
    addseg(wd3, 64, 128, 64);
    for (int i = 0; i < 4; ++i) addseg(w3 + (size_t)i * 147456, 128, 128, 64);
    addseg(wd4, 128, 256, 64);
    for (int i = 0; i < 4; ++i) addseg(w4 + (size_t)i * 589824, 256, 256, 64);
    for (int i = 0; i < 3; ++i) addseg(w5 + (size_t)i * 589824, 256, 256, 64);
    wa.total = cum;  // 5,299,200
    reorder_all<<<(cum + 255) / 256, 256, 0, stream>>>(wa, rwbase);

    // ---- zero-init sparse-written buffers + counters ----
    hipMemsetAsync(cnt, 0, 2 * sizeof(int), stream);
    hipMemsetAsync(Q, 0, 2 * 16777216 * sizeof(_Float16), stream);  // Q + R adjacent
    hipMemsetAsync(x1o, 0, 16777216 * sizeof(float), stream);

    // ---- masks + x0 + fused compaction ----
    {
        int n = B * 512 * 512;
        mask_make<<<(n + 255) / 256, 256, 0, stream>>>(x, mask_p, m1, P, act, cnt, B, 512 * 512);
        mask_down<<<(B * 256 * 256 + 255) / 256, 256, 0, stream>>>(m1, m2, B, 512, 512, 256, 256);
        mask_down<<<(B * 128 * 128 + 255) / 256, 256, 0, stream>>>(m2, m3, B, 256, 256, 128, 128);
        mask_down<<<(B * 64 * 64 + 255) / 256, 256, 0, stream>>>(m3, m4, B, 128, 128, 64, 64);
    }

    auto conv = [&](const _Float16* in, const _Float16* rwp, const float* sp, const float* tp,
                    const float* mk, const _Float16* rs, float* o32, _Float16* o16,
                    int Cin, int Cout, int Hin, int Win, int stride, int CK, int BN) {
        int Hout = Hin / stride, Wout = Win / stride, HWo = Hout * Wout;
        int TW = (Wout < BN) ? Wout : BN;
        int TH = BN / TW;
        dim3 grid(HWo / BN, Cout / 64, B);
        if (CK == 32)
            conv_mfma<64, 64, 32><<<grid, 256, 0, stream>>>(in, rwp, sp, tp, mk, rs, o32, o16,
                Cin, Cout, Hin, Win, Hout, Wout, TH, TW, stride, 1);
        else if (BN == 64)
            conv_mfma<64, 64, 64><<<grid, 256, 0, stream>>>(in, rwp, sp, tp, mk, rs, o32, o16,
                Cin, Cout, Hin, Win, Hout, Wout, TH, TW, stride, 1);
        else
            conv_mfma<64, 32, 64><<<grid, 256, 0, stream>>>(in, rwp, sp, tp, mk, rs, o32, o16,
                Cin, Cout, Hin, Win, Hout, Wout, TH, TW, stride, 1);
    };
    auto sconv = [&](const _Float16* in, const _Float16* rwp, const float* sp, const float* tp,
                     const _Float16* rs, float* o32, _Float16* o16) {
        dim3 grid(1024, 1, B);
        conv_sparse<<<grid, 256, 0, stream>>>(in, rwp, sp, tp, act, cnt, rs, o32, o16, 512, 512, 1);
    };

    // ---- stage 1 (32ch, 512x512) sparse: P=x0 ----
    sconv(P, rp[0], s1 + 0,   t1 + 0,   nullptr, nullptr, Q);
    sconv(Q, rp[1], s1 + 32,  t1 + 32,  nullptr, nullptr, R);
    sconv(R, rp[2], s1 + 64,  t1 + 64,  Q,       nullptr, P);   // P inactive sites = 0 from x0
    sconv(P, rp[3], s1 + 96,  t1 + 96,  nullptr, nullptr, Q);
    sconv(Q, rp[4], s1 + 128, t1 + 128, P,       x1o,     R);   // x1 = R

    // ---- stage 2 (32->64, 512->256): in R ----
    conv(R, rp[5], s2 + 0,   t2 + 0,   m2, nullptr, nullptr, P, 32, 64, 512, 512, 2, 32, 64);
    conv(P, rp[6], s2 + 64,  t2 + 64,  m2, nullptr, nullptr, Q, 64, 64, 256, 256, 1, 64, 64);
    conv(Q, rp[7], s2 + 128, t2 + 128, m2, P,       nullptr, P, 64, 64, 256, 256, 1, 64, 64);
    conv(P, rp[8], s2 + 192, t2 + 192, m2, nullptr, nullptr, Q, 64, 64, 256, 256, 1, 64, 64);
    conv(Q, rp[9], s2 + 256, t2 + 256, m2, P,       x2o,     P, 64, 64, 256, 256, 1, 64, 64);

    // ---- stage 3 (64->128, 256->128): x2 = P ----
    conv(P, rp[10], s3 + 0,   t3 + 0,   m3, nullptr, nullptr, Q, 64, 128, 256, 256, 2, 64, 64);
    conv(Q, rp[11], s3 + 128, t3 + 128, m3, nullptr, nullptr, R, 128, 128, 128, 128, 1, 64, 64);
    conv(R, rp[12], s3 + 256, t3 + 256, m3, Q,       nullptr, Q, 128, 128, 128, 128, 1, 64, 64);
    conv(Q, rp[13], s3 + 384, t3 + 384, m3, nullptr, nullptr, R, 128, 128, 128, 128, 1, 64, 64);
    conv(R, rp[14], s3 + 512, t3 + 512, m3, Q,       x3o,     Q, 128, 128, 128, 128, 1, 64, 64);

    // ---- stage 4 (128->256, 128->64): x3 = Q, BN=32 for grid parallelism ----
    conv(Q, rp[15], s4 + 0,    t4 + 0,    m4, nullptr, nullptr, P, 128, 256, 128, 128, 2, 64, 32);
    conv(P, rp[16], s4 + 256,  t4 + 256,  m4, nullptr, nullptr, R, 256, 256, 64, 64, 1, 64, 32);
    conv(R, rp[17], s4 + 512,  t4 + 512,  m4, P,       nullptr, P, 256, 256, 64, 64, 1, 64, 32);
    conv(P, rp[18], s4 + 768,  t4 + 768,  m4, nullptr, nullptr, R, 256, 256, 64, 64, 1, 64, 32);
    conv(R, rp[19], s4 + 1024, t4 + 1024, m4, P,       x4o,     P, 256, 256, 64, 64, 1, 64, 32);

    // ---- conv5 (dense): x4 = P, BN=32 ----
    conv(P, rp[20], s5 + 0,   t5 + 0,   nullptr, nullptr, nullptr, Q, 256, 256, 64, 64, 2, 64, 32);
    conv(Q, rp[21], s5 + 256, t5 + 256, nullptr, nullptr, nullptr, R, 256, 256, 32, 32, 1, 64, 32);
    conv(R, rp[22], s5 + 512, t5 + 512, nullptr, nullptr, x5o, nullptr, 256, 256, 32, 32, 1, 64, 32);
}

// Round 11
// 1086.489 us; speedup vs baseline: 1.1150x; 1.1150x over previous
//
#include <hip/hip_runtime.h>

typedef __attribute__((ext_vector_type(8))) _Float16 f16x8;
typedef __attribute__((ext_vector_type(4))) _Float16 f16x4;
typedef __attribute__((ext_vector_type(4))) float f32x4;

// ---------------------------------------------------------------------------
// mask_make: m = (mask_p < 0.1); x0 = fp16 blocked [b][pix][32] of x*mask;
// fused block-aggregated active-site compaction (1 global atomic / block).
// ---------------------------------------------------------------------------
__global__ void mask_make(const float* __restrict__ x, const float* __restrict__ mp,
                          float* __restrict__ m, _Float16* __restrict__ x0,
                          int* __restrict__ act, int* __restrict__ cnt,
                          int B, int HW) {
    int i = blockIdx.x * blockDim.x + threadIdx.x;
    const int tid = threadIdx.x;
    const int lane = tid & 63;
    const int wv = tid >> 6;
    bool active = (mp[i] < 0.1f);
    float mv = active ? 1.0f : 0.0f;
    m[i] = mv;
    int b = i / HW, p = i - b * HW;           // b uniform per block (HW % 256 == 0)
    const float* xb = x + ((size_t)b * 32) * HW + p;
    _Float16* ob = x0 + (size_t)i * 32;
    #pragma unroll
    for (int c = 0; c < 32; ++c) ob[c] = (_Float16)(xb[(size_t)c * HW] * mv);

    __shared__ int wcnt[4];
    __shared__ int bbase;
    unsigned long long ball = __ballot(active);
    int wtot = __popcll(ball);
    int prefix = __popcll(ball & ((1ull << lane) - 1ull));
    if (lane == 0) wcnt[wv] = wtot;
    __syncthreads();
    if (tid == 0) {
        int s = 0;
        #pragma unroll
        for (int w = 0; w < 4; ++w) { int tv = wcnt[w]; wcnt[w] = s; s += tv; }
        bbase = (s > 0) ? atomicAdd(&cnt[b], s) : 0;
    }
    __syncthreads();
    if (active) act[b * HW + bbase + wcnt[wv] + prefix] = p;
}

// 3x3 stride-2 pad-1 max-pool on (B,1,H,W) mask
__global__ void mask_down(const float* __restrict__ mi, float* __restrict__ mo,
                          int B, int Hi, int Wi, int Ho, int Wo) {
    int i = blockIdx.x * blockDim.x + threadIdx.x;
    if (i >= B * Ho * Wo) return;
    int wo = i % Wo;
    int t = i / Wo;
    int ho = t % Ho;
    int b = t / Ho;
    float v = 0.0f;
    #pragma unroll
    for (int kh = 0; kh < 3; ++kh) {
        int hi = ho * 2 + kh - 1;
        if (hi < 0 || hi >= Hi) continue;
        #pragma unroll
        for (int kw = 0; kw < 3; ++kw) {
            int wi = wo * 2 + kw - 1;
            if (wi < 0 || wi >= Wi) continue;
            v = fmaxf(v, mi[((size_t)b * Hi + hi) * Wi + wi]);
        }
    }
    mo[i] = v;
}

// ---------------------------------------------------------------------------
// Fused weight reorder: all 23 tensors, fp32 OIHW -> fp16 [chunk][co][CK]
// ---------------------------------------------------------------------------
struct WSeg { const float* src; int cin, cout, ck, cum; };
struct WArgs { WSeg seg[23]; int total; };

__global__ void reorder_all(WArgs A, _Float16* __restrict__ rw) {
    int idx = blockIdx.x * 256 + threadIdx.x;
    if (idx >= A.total) return;
    int s = 0;
    #pragma unroll
    for (int k = 1; k < 23; ++k) if (idx >= A.seg[k].cum) s = k;
    WSeg g = A.seg[s];
    int local = idx - g.cum;
    int kk = local % g.ck;
    int t2 = local / g.ck;
    int co = t2 % g.cout;
    int chunk = t2 / g.cout;
    int chunkc = g.cin / g.ck;
    int tap = chunk / chunkc, cc = chunk - tap * chunkc;
    int ci = cc * g.ck + kk;
    rw[g.cum + local] = (_Float16)g.src[((size_t)co * g.cin + ci) * 9 + tap];
}

// ---------------------------------------------------------------------------
// Dense implicit-GEMM conv3x3 (pad1, stride 1/2), fp16 MFMA, fp32 accum.
// Round-6 measured-best variant: BN=64, depth-1 prefetch, awA/awB weight dbuf.
// ---------------------------------------------------------------------------
template<int BM, int BN, int CK>
__global__ __launch_bounds__(256, 4)
void conv_mfma(const _Float16* __restrict__ in, const _Float16* __restrict__ rw,
               const float* __restrict__ s, const float* __restrict__ t,
               const float* __restrict__ mask, const _Float16* __restrict__ res,
               float* __restrict__ out32, _Float16* __restrict__ out16,
               int Cin, int Cout, int Hin, int Win, int Hout, int Wout,
               int TH, int TW, int stride, int relu)
{
    constexpr int WM = BM / 2;
    constexpr int WAVES_N = 2;
    constexpr int WN = BN / WAVES_N;
    constexpr int MR = WM / 16;
    constexpr int NR = WN / 16;
    constexpr int KH = CK / 32;
    constexpr int ELEMS = (CK * BN) / 256;
    constexpr int NV = ELEMS / 8;
    constexpr int TPP = 256 / BN;
    constexpr int LDST = CK + 8;

    __shared__ _Float16 Bsm[2][BN * LDST];

    const int tid = threadIdx.x;
    const int lane = tid & 63;
    const int wv = tid >> 6;
    const int wm = wv >> 1;
    const int wn = wv & 1;
    const int row = lane & 15, q = lane >> 4;

    const int tilesX = Wout / TW;
    const int oy0 = (blockIdx.x / tilesX) * TH;
    const int ox0 = (blockIdx.x % tilesX) * TW;
    const int co0 = blockIdx.y * BM;
    const int b = blockIdx.z;

    const int HWin = Hin * Win;
    const int HWo = Hout * Wout;
    const int cicn = Cin >> 5;
    const int cocn = Cout >> 5;
    const int chunkc = Cin / CK;
    const int nIter = 9 * chunkc;

    const int sn = tid / TPP;
    const int kb = (tid % TPP) * ELEMS;
    const int sty = sn / TW;
    const int stx = sn - sty * TW;
    const int soy = oy0 + sty;
    const int sox = ox0 + stx;

    f32x4 acc[MR][NR];
    #pragma unroll
    for (int m = 0; m < MR; ++m)
        #pragma unroll
        for (int n = 0; n < NR; ++n)
            #pragma unroll
            for (int r = 0; r < 4; ++r) acc[m][n][r] = 0.0f;

    auto LOADG = [&](int c, f16x8* dst) {
        int tap = c / chunkc, cc = c - tap * chunkc;
        int iy = soy * stride + (tap / 3) - 1;
        int ix = sox * stride + (tap - (tap / 3) * 3) - 1;
        bool ok = (iy >= 0 && iy < Hin && ix >= 0 && ix < Win);
        size_t pixoff = (size_t)iy * Win + ix;
        #pragma unroll
        for (int i = 0; i < NV; ++i) {
            int k = kb + 8 * i;
            const _Float16* p = in +
                (((size_t)(b * cicn + cc * KH + (k >> 5)) * HWin + pixoff) << 5) + (k & 31);
            dst[i] = ok ? *(const f16x8*)p : f16x8{};
        }
    };
    auto LOADW = [&](int c, f16x8 (&dst)[KH][MR]) {
        #pragma unroll
        for (int m = 0; m < MR; ++m) {
            int co = co0 + wm * WM + m * 16 + row;
            const _Float16* ap = rw + ((size_t)c * Cout + co) * CK + (q << 3);
            #pragma unroll
            for (int h = 0; h < KH; ++h) dst[h][m] = *(const f16x8*)(ap + 32 * h);
        }
    };
    auto WLDS = [&](int buf, const f16x8* v) {
        #pragma unroll
        for (int i = 0; i < NV; ++i)
            *(f16x8*)&Bsm[buf][sn * LDST + kb + 8 * i] = v[i];
    };
    auto DO_CHUNK = [&](const _Float16* bp, f16x8 (&awx)[KH][MR]) {
        f16x8 bh[KH][NR];
        #pragma unroll
        for (int n = 0; n < NR; ++n) {
            int nl = wn * WN + n * 16 + row;
            const _Float16* bb = bp + nl * LDST + (q << 3);
            #pragma unroll
            for (int h = 0; h < KH; ++h) bh[h][n] = *(const f16x8*)(bb + 32 * h);
        }
        #pragma unroll
        for (int h = 0; h < KH; ++h)
            #pragma unroll
            for (int m = 0; m < MR; ++m)
                #pragma unroll
                for (int n = 0; n < NR; ++n)
                    acc[m][n] = __builtin_amdgcn_mfma_f32_16x16x32_f16(awx[h][m], bh[h][n], acc[m][n], 0, 0, 0);
    };

    f16x8 awA[KH][MR], awB[KH][MR];
    f16x8 v[NV];
    LOADG(0, v);
    LOADW(0, awA);
    WLDS(0, v);
    __syncthreads();

    for (int c = 0; c < nIter; c += 2) {
        f16x8 v2[NV];
        bool h1 = (c + 1) < nIter;
        if (h1) { LOADG(c + 1, v2); LOADW(c + 1, awB); }
        DO_CHUNK(&Bsm[0][0], awA);
        if (h1) WLDS(1, v2);
        __syncthreads();
        if (!h1) break;
        f16x8 v3[NV];
        bool h2 = (c + 2) < nIter;
        if (h2) { LOADG(c + 2, v3); LOADW(c + 2, awA); }
        DO_CHUNK(&Bsm[1][0], awB);
        if (h2) WLDS(0, v3);
        __syncthreads();
    }

    int pix[NR]; float mv[NR];
    #pragma unroll
    for (int n = 0; n < NR; ++n) {
        int nl = wn * WN + n * 16 + row;
        int ty = nl / TW, tx = nl - ty * TW;
        pix[n] = (oy0 + ty) * Wout + (ox0 + tx);
        mv[n] = mask ? mask[(size_t)b * HWo + pix[n]] : 1.0f;
    }
    #pragma unroll
    for (int m = 0; m < MR; ++m) {
        int cb = co0 + wm * WM + m * 16 + q * 4;
        float sc[4], sh[4];
        #pragma unroll
        for (int r = 0; r < 4; ++r) { sc[r] = s[cb + r]; sh[r] = t[cb + r]; }
        #pragma unroll
        for (int n = 0; n < NR; ++n) {
            size_t boff = ((size_t)(b * cocn + (cb >> 5)) * HWo + pix[n]) * 32 + (cb & 31);
            float val[4];
            #pragma unroll
            for (int r = 0; r < 4; ++r) val[r] = (acc[m][n][r] * sc[r] + sh[r]) * mv[n];
            if (res) {
                f16x4 rv = *(const f16x4*)&res[boff];
                #pragma unroll
                for (int r = 0; r < 4; ++r) val[r] += (float)rv[r];
            }
            if (relu) {
                #pragma unroll
                for (int r = 0; r < 4; ++r) val[r] = fmaxf(val[r], 0.0f);
            }
            if (out16) {
                f16x4 pk;
                #pragma unroll
                for (int r = 0; r < 4; ++r) pk[r] = (_Float16)val[r];
                *(f16x4*)&out16[boff] = pk;
            }
            if (out32) {
                #pragma unroll
                for (int r = 0; r < 4; ++r)
                    out32[((size_t)b * Cout + cb + r) * HWo + pix[n]] = val[r];
            }
        }
    }
}

// ---------------------------------------------------------------------------
// Barrier-free dense conv (late stages): wave = 16 pixels x 64 cout.
// Lane (row,q) global-loads its B-fragment (16B of pixel's 64B channel block)
// and 4 A-fragments (L2-broadcast). No LDS, no syncthreads. CK=32 weights.
// ---------------------------------------------------------------------------
__global__ __launch_bounds__(256, 4)
void conv_bf(const _Float16* __restrict__ in, const _Float16* __restrict__ rw,
             const float* __restrict__ s, const float* __restrict__ t,
             const float* __restrict__ mask, const _Float16* __restrict__ res,
             float* __restrict__ out32, _Float16* __restrict__ out16,
             int Cin, int Cout, int Hin, int Win, int Hout, int Wout,
             int stride, int relu)
{
    const int lane = threadIdx.x & 63;
    const int wv = threadIdx.x >> 6;
    const int row = lane & 15, q = lane >> 4;
    const int b = blockIdx.z;
    const int HWo = Hout * Wout;
    const int ntile = HWo >> 4;
    const int gw = blockIdx.x * 4 + wv;
    const int tile = gw % ntile;
    const int cog = gw / ntile;
    const int co0 = cog * 64;
    const int HWin = Hin * Win;
    const int cicn = Cin >> 5;
    const int cocn = Cout >> 5;
    const int nIter = 9 * cicn;

    const int pix = tile * 16 + row;
    const int py = pix / Wout, px_ = pix - py * Wout;
    const int iy0 = py * stride - 1, ix0 = px_ * stride - 1;
    const _Float16* inb = in + (((size_t)b * cicn) * HWin << 5);

    f32x4 acc[4];
    #pragma unroll
    for (int m = 0; m < 4; ++m)
        #pragma unroll
        for (int r = 0; r < 4; ++r) acc[m][r] = 0.0f;

    auto LOADB = [&](int c, f16x8& dst) {
        int tap = c / cicn, cc = c - tap * cicn;
        int iy = iy0 + tap / 3, ix = ix0 + tap - (tap / 3) * 3;
        bool ok = (iy >= 0 && iy < Hin && ix >= 0 && ix < Win);
        dst = ok ? *(const f16x8*)(inb + (((size_t)cc * HWin + (size_t)iy * Win + ix) << 5) + (q << 3))
                 : f16x8{};
    };
    auto LOADA = [&](int c, f16x8 (&dst)[4]) {
        const _Float16* ap = rw + ((size_t)c * Cout + co0 + row) * 32 + (q << 3);
        #pragma unroll
        for (int m = 0; m < 4; ++m) dst[m] = *(const f16x8*)(ap + (size_t)m * 512);
    };

    f16x8 aA[4], aB[4], bfA, bfB;
    LOADB(0, bfA); LOADA(0, aA);
    for (int c = 0; c < nIter; c += 2) {
        bool h1 = (c + 1) < nIter, h2 = (c + 2) < nIter;
        if (h1) { LOADB(c + 1, bfB); LOADA(c + 1, aB); }
        #pragma unroll
        for (int m = 0; m < 4; ++m)
            acc[m] = __builtin_amdgcn_mfma_f32_16x16x32_f16(aA[m], bfA, acc[m], 0, 0, 0);
        if (h2) { LOADB(c + 2, bfA); LOADA(c + 2, aA); }
        if (h1) {
            #pragma unroll
            for (int m = 0; m < 4; ++m)
                acc[m] = __builtin_amdgcn_mfma_f32_16x16x32_f16(aB[m], bfB, acc[m], 0, 0, 0);
        }
    }

    float mv = mask ? mask[(size_t)b * HWo + pix] : 1.0f;
    #pragma unroll
    for (int m = 0; m < 4; ++m) {
        int cb = co0 + m * 16 + q * 4;
        size_t boff = ((size_t)(b * cocn + (cb >> 5)) * HWo + pix) * 32 + (cb & 31);
        float val[4];
        #pragma unroll
        for (int r = 0; r < 4; ++r) val[r] = (acc[m][r] * s[cb + r] + t[cb + r]) * mv;
        if (res) {
            f16x4 rv = *(const f16x4*)&res[boff];
            #pragma unroll
            for (int r = 0; r < 4; ++r) val[r] += (float)rv[r];
        }
        if (relu) {
            #pragma unroll
            for (int r = 0; r < 4; ++r) val[r] = fmaxf(val[r], 0.0f);
        }
        if (out16) {
            f16x4 pk;
            #pragma unroll
            for (int r = 0; r < 4; ++r) pk[r] = (_Float16)val[r];
            *(f16x4*)&out16[boff] = pk;
        }
        if (out32) {
            #pragma unroll
            for (int r = 0; r < 4; ++r)
                out32[((size_t)b * Cout + cb + r) * HWo + pix] = val[r];
        }
    }
}

// ---------------------------------------------------------------------------
// Sparse stage-1 conv, barrier-free: Cin=Cout=32 gathered over active list.
// ---------------------------------------------------------------------------
__global__ __launch_bounds__(256, 4)
void conv_sparse(const _Float16* __restrict__ in, const _Float16* __restrict__ rw,
                 const float* __restrict__ s, const float* __restrict__ t,
                 const int* __restrict__ act, const int* __restrict__ cnt,
                 const _Float16* __restrict__ res,
                 float* __restrict__ out32, _Float16* __restrict__ out16,
                 int Hin, int Win, int relu)
{
    const int tid = threadIdx.x;
    const int lane = tid & 63;
    const int wv = tid >> 6;
    const int row = lane & 15, q = lane >> 4;
    const int b = blockIdx.z;
    const int HW = Hin * Win;
    const int nb = cnt[b];
    const int base = (blockIdx.x * 4 + wv) * 16;
    if (base >= nb) return;

    const int* actb = act + b * HW;
    const _Float16* inb = in + ((size_t)b * HW << 5);

    int j = base + row;
    bool vn = j < nb;
    int pn = vn ? actb[j] : 0;
    int py = pn / Win, px = pn - py * Win;

    f32x4 acc0, acc1;
    #pragma unroll
    for (int r = 0; r < 4; ++r) { acc0[r] = 0.0f; acc1[r] = 0.0f; }

    #pragma unroll
    for (int c = 0; c < 9; ++c) {
        const int dy = c / 3 - 1, dx = c - (c / 3) * 3 - 1;
        f16x8 a0 = *(const f16x8*)(rw + ((size_t)c * 32 + row) * 32 + (q << 3));
        f16x8 a1 = *(const f16x8*)(rw + ((size_t)c * 32 + 16 + row) * 32 + (q << 3));
        int iy = py + dy, ix = px + dx;
        bool ok = vn && iy >= 0 && iy < Hin && ix >= 0 && ix < Win;
        f16x8 bf = ok ? *(const f16x8*)(inb + ((size_t)(iy * Win + ix) << 5) + (q << 3))
                      : f16x8{};
        acc0 = __builtin_amdgcn_mfma_f32_16x16x32_f16(a0, bf, acc0, 0, 0, 0);
        acc1 = __builtin_amdgcn_mfma_f32_16x16x32_f16(a1, bf, acc1, 0, 0, 0);
    }

    if (!vn) return;
    size_t pbase = ((size_t)b * HW + pn) << 5;
    #pragma unroll
    for (int m = 0; m < 2; ++m) {
        const f32x4& am = m ? acc1 : acc0;
        int cb = m * 16 + q * 4;
        float val[4];
        #pragma unroll
        for (int r = 0; r < 4; ++r) val[r] = am[r] * s[cb + r] + t[cb + r];
        if (res) {
            f16x4 rv = *(const f16x4*)&res[pbase + cb];
            #pragma unroll
            for (int r = 0; r < 4; ++r) val[r] += (float)rv[r];
        }
        if (relu) {
            #pragma unroll
            for (int r = 0; r < 4; ++r) val[r] = fmaxf(val[r], 0.0f);
        }
        f16x4 pk;
        #pragma unroll
        for (int r = 0; r < 4; ++r) pk[r] = (_Float16)val[r];
        *(f16x4*)&out16[pbase + cb] = pk;
        if (out32) {
            #pragma unroll
            for (int r = 0; r < 4; ++r)
                out32[((size_t)(b * 32 + cb + r)) * HW + pn] = val[r];
        }
    }
}

extern "C" void kernel_launch(void* const* d_in, const int* in_sizes, int n_in,
                              void* d_out, int out_size, void* d_ws, size_t ws_size,
                              hipStream_t stream) {
    const int B = 2;

    const float* x      = (const float*)d_in[0];
    const float* mask_p = (const float*)d_in[1];
    const float* w1  = (const float*)d_in[2];
    const float* s1  = (const float*)d_in[3];
    const float* t1  = (const float*)d_in[4];
    const float* wd2 = (const float*)d_in[5];
    const float* w2  = (const float*)d_in[6];
    const float* s2  = (const float*)d_in[7];
    const float* t2  = (const float*)d_in[8];
    const float* wd3 = (const float*)d_in[9];
    const float* w3  = (const float*)d_in[10];
    const float* s3  = (const float*)d_in[11];
    const float* t3  = (const float*)d_in[12];
    const float* wd4 = (const float*)d_in[13];
    const float* w4  = (const float*)d_in[14];
    const float* s4  = (const float*)d_in[15];
    const float* t4  = (const float*)d_in[16];
    const float* w5  = (const float*)d_in[17];
    const float* s5  = (const float*)d_in[18];
    const float* t5  = (const float*)d_in[19];

    // d_out slices (fp32 NCHW)
    float* x1o = (float*)d_out;
    float* x2o = x1o + 16777216;
    float* x3o = x2o + 8388608;
    float* x4o = x3o + 4194304;
    float* x5o = x4o + 2097152;

    // workspace
    _Float16* rwbase = (_Float16*)d_ws;        // 5,299,200 halves
    float* m1 = (float*)d_ws + 2649600;
    float* m2 = m1 + 524288;
    float* m3 = m2 + 131072;
    float* m4 = m3 + 32768;
    int* act  = (int*)(m4 + 8192);             // 524288 ints
    int* cnt  = act + 524288;                  // 2 ints (+pad)
    _Float16* P = (_Float16*)(cnt + 32);
    _Float16* Q = P + 16777216;
    _Float16* R = Q + 16777216;

    // ---- fused weight reorder (1 launch) ----
    WArgs wa;
    int cum = 0, si = 0;
    const _Float16* rp[23];
    auto addseg = [&](const float* src, int cin, int cout, int ck) {
        wa.seg[si].src = src; wa.seg[si].cin = cin; wa.seg[si].cout = cout;
        wa.seg[si].ck = ck; wa.seg[si].cum = cum;
        rp[si] = rwbase + cum;
        cum += cout * cin * 9; si++;
    };
    for (int i = 0; i < 5; ++i) addseg(w1 + (size_t)i * 9216, 32, 32, 32);
    addseg(wd2, 32, 64, 32);
    for (int i = 0; i < 4; ++i) addseg(w2 + (size_t)i * 36864, 64, 64, 64);
    addseg(wd3, 64, 128, 64);
    for (int i = 0; i < 4; ++i) addseg(w3 + (size_t)i * 147456, 128, 128, 64);
    addseg(wd4, 128, 256, 32);                 // CK=32 for conv_bf
    for (int i = 0; i < 4; ++i) addseg(w4 + (size_t)i * 589824, 256, 256, 32);
    for (int i = 0; i < 3; ++i) addseg(w5 + (size_t)i * 589824, 256, 256, 32);
    wa.total = cum;  // 5,299,200
    reorder_all<<<(cum + 255) / 256, 256, 0, stream>>>(wa, rwbase);

    // ---- zero-init sparse-written buffers + counters ----
    hipMemsetAsync(cnt, 0, 2 * sizeof(int), stream);
    hipMemsetAsync(Q, 0, 2 * 16777216 * sizeof(_Float16), stream);  // Q + R adjacent
    hipMemsetAsync(x1o, 0, 16777216 * sizeof(float), stream);

    // ---- masks + x0 + fused compaction ----
    {
        int n = B * 512 * 512;
        mask_make<<<(n + 255) / 256, 256, 0, stream>>>(x, mask_p, m1, P, act, cnt, B, 512 * 512);
        mask_down<<<(B * 256 * 256 + 255) / 256, 256, 0, stream>>>(m1, m2, B, 512, 512, 256, 256);
        mask_down<<<(B * 128 * 128 + 255) / 256, 256, 0, stream>>>(m2, m3, B, 256, 256, 128, 128);
        mask_down<<<(B * 64 * 64 + 255) / 256, 256, 0, stream>>>(m3, m4, B, 128, 128, 64, 64);
    }

    auto conv = [&](const _Float16* in, const _Float16* rwp, const float* sp, const float* tp,
                    const float* mk, const _Float16* rs, float* o32, _Float16* o16,
                    int Cin, int Cout, int Hin, int Win, int stride, int CK) {
        int Hout = Hin / stride, Wout = Win / stride, HWo = Hout * Wout;
        int TW = (Wout < 64) ? Wout : 64;
        int TH = 64 / TW;
        dim3 grid(HWo / 64, Cout / 64, B);
        if (CK == 32)
            conv_mfma<64, 64, 32><<<grid, 256, 0, stream>>>(in, rwp, sp, tp, mk, rs, o32, o16,
                Cin, Cout, Hin, Win, Hout, Wout, TH, TW, stride, 1);
        else
            conv_mfma<64, 64, 64><<<grid, 256, 0, stream>>>(in, rwp, sp, tp, mk, rs, o32, o16,
                Cin, Cout, Hin, Win, Hout, Wout, TH, TW, stride, 1);
    };
    auto bconv = [&](const _Float16* in, const _Float16* rwp, const float* sp, const float* tp,
                     const float* mk, const _Float16* rs, float* o32, _Float16* o16,
                     int Cin, int Cout, int Hin, int Win, int stride) {
        int Hout = Hin / stride, Wout = Win / stride, HWo = Hout * Wout;
        int waves = (HWo / 16) * (Cout / 64);
        dim3 grid(waves / 4, 1, B);
        conv_bf<<<grid, 256, 0, stream>>>(in, rwp, sp, tp, mk, rs, o32, o16,
            Cin, Cout, Hin, Win, Hout, Wout, stride, 1);
    };
    auto sconv = [&](const _Float16* in, const _Float16* rwp, const float* sp, const float* tp,
                     const _Float16* rs, float* o32, _Float16* o16) {
        dim3 grid(1024, 1, B);
        conv_sparse<<<grid, 256, 0, stream>>>(in, rwp, sp, tp, act, cnt, rs, o32, o16, 512, 512, 1);
    };

    // ---- stage 1 (32ch, 512x512) sparse: P=x0 ----
    sconv(P, rp[0], s1 + 0,   t1 + 0,   nullptr, nullptr, Q);
    sconv(Q, rp[1], s1 + 32,  t1 + 32,  nullptr, nullptr, R);
    sconv(R, rp[2], s1 + 64,  t1 + 64,  Q,       nullptr, P);   // P inactive sites = 0 from x0
    sconv(P, rp[3], s1 + 96,  t1 + 96,  nullptr, nullptr, Q);
    sconv(Q, rp[4], s1 + 128, t1 + 128, P,       x1o,     R);   // x1 = R

    // ---- stage 2 (32->64, 512->256): in R ----
    conv(R, rp[5], s2 + 0,   t2 + 0,   m2, nullptr, nullptr, P, 32, 64, 512, 512, 2, 32);
    conv(P, rp[6], s2 + 64,  t2 + 64,  m2, nullptr, nullptr, Q, 64, 64, 256, 256, 1, 64);
    conv(Q, rp[7], s2 + 128, t2 + 128, m2, P,       nullptr, P, 64, 64, 256, 256, 1, 64);
    conv(P, rp[8], s2 + 192, t2 + 192, m2, nullptr, nullptr, Q, 64, 64, 256, 256, 1, 64);
    conv(Q, rp[9], s2 + 256, t2 + 256, m2, P,       x2o,     P, 64, 64, 256, 256, 1, 64);

    // ---- stage 3 (64->128, 256->128): x2 = P ----
    conv(P, rp[10], s3 + 0,   t3 + 0,   m3, nullptr, nullptr, Q, 64, 128, 256, 256, 2, 64);
    conv(Q, rp[11], s3 + 128, t3 + 128, m3, nullptr, nullptr, R, 128, 128, 128, 128, 1, 64);
    conv(R, rp[12], s3 + 256, t3 + 256, m3, Q,       nullptr, Q, 128, 128, 128, 128, 1, 64);
    conv(Q, rp[13], s3 + 384, t3 + 384, m3, nullptr, nullptr, R, 128, 128, 128, 128, 1, 64);
    conv(R, rp[14], s3 + 512, t3 + 512, m3, Q,       x3o,     Q, 128, 128, 128, 128, 1, 64);

    // ---- stage 4 (128->256, 128->64): x3 = Q, barrier-free ----
    bconv(Q, rp[15], s4 + 0,    t4 + 0,    m4, nullptr, nullptr, P, 128, 256, 128, 128, 2);
    bconv(P, rp[16], s4 + 256,  t4 + 256,  m4, nullptr, nullptr, R, 256, 256, 64, 64, 1);
    bconv(R, rp[17], s4 + 512,  t4 + 512,  m4, P,       nullptr, P, 256, 256, 64, 64, 1);
    bconv(P, rp[18], s4 + 768,  t4 + 768,  m4, nullptr, nullptr, R, 256, 256, 64, 64, 1);
    bconv(R, rp[19], s4 + 1024, t4 + 1024, m4, P,       x4o,     P, 256, 256, 64, 64, 1);

    // ---- conv5 (dense): x4 = P, barrier-free ----
    bconv(P, rp[20], s5 + 0,   t5 + 0,   nullptr, nullptr, nullptr, Q, 256, 256, 64, 64, 2);
    bconv(Q, rp[21], s5 + 256, t5 + 256, nullptr, nullptr, nullptr, R, 256, 256, 32, 32, 1);
    bconv(R, rp[22], s5 + 512, t5 + 512, nullptr, nullptr, x5o, nullptr, 256, 256, 32, 32, 1);
}

// Round 12
// 928.112 us; speedup vs baseline: 1.3052x; 1.1706x over previous
//
#include <hip/hip_runtime.h>

typedef __attribute__((ext_vector_type(8))) _Float16 f16x8;
typedef __attribute__((ext_vector_type(4))) _Float16 f16x4;
typedef __attribute__((ext_vector_type(4))) float f32x4;

// ---------------------------------------------------------------------------
// mask_make: m = (mask_p < 0.1); x0 = fp16 blocked [b][pix][32] of x*mask;
// fused block-aggregated active-site compaction (1 global atomic / block).
// ---------------------------------------------------------------------------
__global__ void mask_make(const float* __restrict__ x, const float* __restrict__ mp,
                          float* __restrict__ m, _Float16* __restrict__ x0,
                          int* __restrict__ act, int* __restrict__ cnt,
                          int B, int HW) {
    int i = blockIdx.x * blockDim.x + threadIdx.x;
    const int tid = threadIdx.x;
    const int lane = tid & 63;
    const int wv = tid >> 6;
    bool active = (mp[i] < 0.1f);
    float mv = active ? 1.0f : 0.0f;
    m[i] = mv;
    int b = i / HW, p = i - b * HW;           // b uniform per block (HW % 256 == 0)
    const float* xb = x + ((size_t)b * 32) * HW + p;
    _Float16* ob = x0 + (size_t)i * 32;
    #pragma unroll
    for (int c = 0; c < 32; ++c) ob[c] = (_Float16)(xb[(size_t)c * HW] * mv);

    __shared__ int wcnt[4];
    __shared__ int bbase;
    unsigned long long ball = __ballot(active);
    int wtot = __popcll(ball);
    int prefix = __popcll(ball & ((1ull << lane) - 1ull));
    if (lane == 0) wcnt[wv] = wtot;
    __syncthreads();
    if (tid == 0) {
        int s = 0;
        #pragma unroll
        for (int w = 0; w < 4; ++w) { int tv = wcnt[w]; wcnt[w] = s; s += tv; }
        bbase = (s > 0) ? atomicAdd(&cnt[b], s) : 0;
    }
    __syncthreads();
    if (active) act[b * HW + bbase + wcnt[wv] + prefix] = p;
}

// 3x3 stride-2 pad-1 max-pool on (B,1,H,W) mask
__global__ void mask_down(const float* __restrict__ mi, float* __restrict__ mo,
                          int B, int Hi, int Wi, int Ho, int Wo) {
    int i = blockIdx.x * blockDim.x + threadIdx.x;
    if (i >= B * Ho * Wo) return;
    int wo = i % Wo;
    int t = i / Wo;
    int ho = t % Ho;
    int b = t / Ho;
    float v = 0.0f;
    #pragma unroll
    for (int kh = 0; kh < 3; ++kh) {
        int hi = ho * 2 + kh - 1;
        if (hi < 0 || hi >= Hi) continue;
        #pragma unroll
        for (int kw = 0; kw < 3; ++kw) {
            int wi = wo * 2 + kw - 1;
            if (wi < 0 || wi >= Wi) continue;
            v = fmaxf(v, mi[((size_t)b * Hi + hi) * Wi + wi]);
        }
    }
    mo[i] = v;
}

// ---------------------------------------------------------------------------
// Fused weight reorder: all 23 tensors, fp32 OIHW -> fp16 [chunk][co][32]
// ---------------------------------------------------------------------------
struct WSeg { const float* src; int cin, cout, ck, cum; };
struct WArgs { WSeg seg[23]; int total; };

__global__ void reorder_all(WArgs A, _Float16* __restrict__ rw) {
    int idx = blockIdx.x * 256 + threadIdx.x;
    if (idx >= A.total) return;
    int s = 0;
    #pragma unroll
    for (int k = 1; k < 23; ++k) if (idx >= A.seg[k].cum) s = k;
    WSeg g = A.seg[s];
    int local = idx - g.cum;
    int kk = local % g.ck;
    int t2 = local / g.ck;
    int co = t2 % g.cout;
    int chunk = t2 / g.cout;
    int chunkc = g.cin / g.ck;
    int tap = chunk / chunkc, cc = chunk - tap * chunkc;
    int ci = cc * g.ck + kk;
    rw[g.cum + local] = (_Float16)g.src[((size_t)co * g.cin + ci) * 9 + tap];
}

// ---------------------------------------------------------------------------
// Dense implicit-GEMM conv3x3 (down convs), fp16 MFMA, fp32 accum.
// ---------------------------------------------------------------------------
template<int BM, int BN, int CK>
__global__ __launch_bounds__(256, 4)
void conv_mfma(const _Float16* __restrict__ in, const _Float16* __restrict__ rw,
               const float* __restrict__ s, const float* __restrict__ t,
               const float* __restrict__ mask, const _Float16* __restrict__ res,
               float* __restrict__ out32, _Float16* __restrict__ out16,
               int Cin, int Cout, int Hin, int Win, int Hout, int Wout,
               int TH, int TW, int stride, int relu)
{
    constexpr int WM = BM / 2;
    constexpr int WAVES_N = 2;
    constexpr int WN = BN / WAVES_N;
    constexpr int MR = WM / 16;
    constexpr int NR = WN / 16;
    constexpr int KH = CK / 32;
    constexpr int ELEMS = (CK * BN) / 256;
    constexpr int NV = ELEMS / 8;
    constexpr int TPP = 256 / BN;
    constexpr int LDST = CK + 8;

    __shared__ _Float16 Bsm[2][BN * LDST];

    const int tid = threadIdx.x;
    const int lane = tid & 63;
    const int wv = tid >> 6;
    const int wm = wv >> 1;
    const int wn = wv & 1;
    const int row = lane & 15, q = lane >> 4;

    const int tilesX = Wout / TW;
    const int oy0 = (blockIdx.x / tilesX) * TH;
    const int ox0 = (blockIdx.x % tilesX) * TW;
    const int co0 = blockIdx.y * BM;
    const int b = blockIdx.z;

    const int HWin = Hin * Win;
    const int HWo = Hout * Wout;
    const int cicn = Cin >> 5;
    const int cocn = Cout >> 5;
    const int chunkc = Cin / CK;
    const int nIter = 9 * chunkc;

    const int sn = tid / TPP;
    const int kb = (tid % TPP) * ELEMS;
    const int sty = sn / TW;
    const int stx = sn - sty * TW;
    const int soy = oy0 + sty;
    const int sox = ox0 + stx;

    f32x4 acc[MR][NR];
    #pragma unroll
    for (int m = 0; m < MR; ++m)
        #pragma unroll
        for (int n = 0; n < NR; ++n)
            #pragma unroll
            for (int r = 0; r < 4; ++r) acc[m][n][r] = 0.0f;

    auto LOADG = [&](int c, f16x8* dst) {
        int tap = c / chunkc, cc = c - tap * chunkc;
        int iy = soy * stride + (tap / 3) - 1;
        int ix = sox * stride + (tap - (tap / 3) * 3) - 1;
        bool ok = (iy >= 0 && iy < Hin && ix >= 0 && ix < Win);
        size_t pixoff = (size_t)iy * Win + ix;
        #pragma unroll
        for (int i = 0; i < NV; ++i) {
            int k = kb + 8 * i;
            const _Float16* p = in +
                (((size_t)(b * cicn + cc * KH + (k >> 5)) * HWin + pixoff) << 5) + (k & 31);
            dst[i] = ok ? *(const f16x8*)p : f16x8{};
        }
    };
    auto LOADW = [&](int c, f16x8 (&dst)[KH][MR]) {
        #pragma unroll
        for (int m = 0; m < MR; ++m) {
            int co = co0 + wm * WM + m * 16 + row;
            const _Float16* ap = rw + ((size_t)c * Cout + co) * CK + (q << 3);
            #pragma unroll
            for (int h = 0; h < KH; ++h) dst[h][m] = *(const f16x8*)(ap + 32 * h);
        }
    };
    auto WLDS = [&](int buf, const f16x8* v) {
        #pragma unroll
        for (int i = 0; i < NV; ++i)
            *(f16x8*)&Bsm[buf][sn * LDST + kb + 8 * i] = v[i];
    };
    auto DO_CHUNK = [&](const _Float16* bp, f16x8 (&awx)[KH][MR]) {
        f16x8 bh[KH][NR];
        #pragma unroll
        for (int n = 0; n < NR; ++n) {
            int nl = wn * WN + n * 16 + row;
            const _Float16* bb = bp + nl * LDST + (q << 3);
            #pragma unroll
            for (int h = 0; h < KH; ++h) bh[h][n] = *(const f16x8*)(bb + 32 * h);
        }
        #pragma unroll
        for (int h = 0; h < KH; ++h)
            #pragma unroll
            for (int m = 0; m < MR; ++m)
                #pragma unroll
                for (int n = 0; n < NR; ++n)
                    acc[m][n] = __builtin_amdgcn_mfma_f32_16x16x32_f16(awx[h][m], bh[h][n], acc[m][n], 0, 0, 0);
    };

    f16x8 awA[KH][MR], awB[KH][MR];
    f16x8 v[NV];
    LOADG(0, v);
    LOADW(0, awA);
    WLDS(0, v);
    __syncthreads();

    for (int c = 0; c < nIter; c += 2) {
        f16x8 v2[NV];
        bool h1 = (c + 1) < nIter;
        if (h1) { LOADG(c + 1, v2); LOADW(c + 1, awB); }
        DO_CHUNK(&Bsm[0][0], awA);
        if (h1) WLDS(1, v2);
        __syncthreads();
        if (!h1) break;
        f16x8 v3[NV];
        bool h2 = (c + 2) < nIter;
        if (h2) { LOADG(c + 2, v3); LOADW(c + 2, awA); }
        DO_CHUNK(&Bsm[1][0], awB);
        if (h2) WLDS(0, v3);
        __syncthreads();
    }

    int pix[NR]; float mv[NR];
    #pragma unroll
    for (int n = 0; n < NR; ++n) {
        int nl = wn * WN + n * 16 + row;
        int ty = nl / TW, tx = nl - ty * TW;
        pix[n] = (oy0 + ty) * Wout + (ox0 + tx);
        mv[n] = mask ? mask[(size_t)b * HWo + pix[n]] : 1.0f;
    }
    #pragma unroll
    for (int m = 0; m < MR; ++m) {
        int cb = co0 + wm * WM + m * 16 + q * 4;
        float sc[4], sh[4];
        #pragma unroll
        for (int r = 0; r < 4; ++r) { sc[r] = s[cb + r]; sh[r] = t[cb + r]; }
        #pragma unroll
        for (int n = 0; n < NR; ++n) {
            size_t boff = ((size_t)(b * cocn + (cb >> 5)) * HWo + pix[n]) * 32 + (cb & 31);
            float val[4];
            #pragma unroll
            for (int r = 0; r < 4; ++r) val[r] = (acc[m][n][r] * sc[r] + sh[r]) * mv[n];
            if (res) {
                f16x4 rv = *(const f16x4*)&res[boff];
                #pragma unroll
                for (int r = 0; r < 4; ++r) val[r] += (float)rv[r];
            }
            if (relu) {
                #pragma unroll
                for (int r = 0; r < 4; ++r) val[r] = fmaxf(val[r], 0.0f);
            }
            if (out16) {
                f16x4 pk;
                #pragma unroll
                for (int r = 0; r < 4; ++r) pk[r] = (_Float16)val[r];
                *(f16x4*)&out16[boff] = pk;
            }
            if (out32) {
                #pragma unroll
                for (int r = 0; r < 4; ++r)
                    out32[((size_t)b * Cout + cb + r) * HWo + pix[n]] = val[r];
            }
        }
    }
}

// ---------------------------------------------------------------------------
// Halo-tile conv3x3 stride-1: load (8+2)x(8+2)xCIN input patch to LDS ONCE,
// then the whole 9-tap K-loop reads LDS (XOR-swizzled slots, <=2-way banks).
// One barrier per block. Weight regs rolling-dbuf (awA/awB), no barriers.
// ---------------------------------------------------------------------------
template<int CIN>
__global__ __launch_bounds__(256, 4)
void conv_halo(const _Float16* __restrict__ in, const _Float16* __restrict__ rw,
               const float* __restrict__ s, const float* __restrict__ t,
               const float* __restrict__ mask, const _Float16* __restrict__ res,
               float* __restrict__ out32, _Float16* __restrict__ out16,
               int Cout, int Hin, int Win,
               int relu)
{
    constexpr int CV = CIN / 8;          // 16B slots per pixel
    constexpr int NPIX = 100;            // 10x10 halo
    constexpr int NI = 9 * (CIN / 32);   // K chunks
    constexpr int TOT = NPIX * CV;

    __shared__ _Float16 Bsm[NPIX * CIN];

    const int tid = threadIdx.x;
    const int lane = tid & 63;
    const int wv = tid >> 6;
    const int wm = wv >> 1;
    const int wn = wv & 1;
    const int row = lane & 15, q = lane >> 4;

    const int Wout = Win, Hout = Hin;
    const int tilesX = Wout >> 3;
    const int oy0 = (blockIdx.x / tilesX) << 3;
    const int ox0 = (blockIdx.x % tilesX) << 3;
    const int co0 = blockIdx.y * 64;
    const int b = blockIdx.z;

    const int HWin = Hin * Win;
    const int cicn = CIN >> 5;
    const int cocn = Cout >> 5;

    // ---- halo load: pixel hp = 10*dyi+dxi at (oy0-1+dyi, ox0-1+dxi) ----
    #pragma unroll
    for (int l = 0; l < (TOT + 255) / 256; ++l) {
        int idx = tid + l * 256;
        if (idx < TOT) {
            int hp = idx / CV, v = idx - hp * CV;
            int hy = oy0 - 1 + hp / 10;
            int hx = ox0 - 1 + hp % 10;
            bool ok = (hy >= 0 && hy < Hin && hx >= 0 && hx < Win);
            f16x8 val = f16x8{};
            if (ok) {
                const _Float16* p = in +
                    (((size_t)(b * cicn + (v >> 2)) * HWin + (size_t)hy * Win + hx) << 5) + ((v & 3) << 3);
                val = *(const f16x8*)p;
            }
            int sw = v ^ (hp & 7);                 // slot swizzle (involution)
            *(f16x8*)&Bsm[hp * CIN + (sw << 3)] = val;
        }
    }
    __syncthreads();

    f32x4 acc[2][2];
    #pragma unroll
    for (int m = 0; m < 2; ++m)
        #pragma unroll
        for (int n = 0; n < 2; ++n)
            #pragma unroll
            for (int r = 0; r < 4; ++r) acc[m][n][r] = 0.0f;

    auto LOADW = [&](int c, f16x8 (&dst)[2]) {
        #pragma unroll
        for (int m = 0; m < 2; ++m) {
            int co = co0 + wm * 32 + m * 16 + row;
            dst[m] = *(const f16x8*)(rw + ((size_t)c * Cout + co) * 32 + (q << 3));
        }
    };

    // n-tile pixel coords (fixed per thread)
    int ty[2], tx[2];
    #pragma unroll
    for (int n = 0; n < 2; ++n) {
        int nl = wn * 32 + n * 16 + row;
        ty[n] = nl >> 3; tx[n] = nl & 7;
    }

    f16x8 awA[2], awB[2];
    LOADW(0, awA);
    #pragma unroll
    for (int c = 0; c < NI; ++c) {
        if (c + 1 < NI) LOADW(c + 1, (c & 1) ? awA : awB);
        const f16x8* aw = (c & 1) ? awB : awA;
        const int tap = c / (CIN / 32), cc = c % (CIN / 32);
        const int dy = tap / 3, dx = tap - dy * 3;
        f16x8 bh[2];
        #pragma unroll
        for (int n = 0; n < 2; ++n) {
            int hp = (ty[n] + dy) * 10 + tx[n] + dx;
            int slot = ((cc << 2) + q) ^ (hp & 7);
            bh[n] = *(const f16x8*)&Bsm[hp * CIN + (slot << 3)];
        }
        #pragma unroll
        for (int m = 0; m < 2; ++m)
            #pragma unroll
            for (int n = 0; n < 2; ++n)
                acc[m][n] = __builtin_amdgcn_mfma_f32_16x16x32_f16(aw[m], bh[n], acc[m][n], 0, 0, 0);
    }

    const int HWo = Hout * Wout;
    int pix[2]; float mv[2];
    #pragma unroll
    for (int n = 0; n < 2; ++n) {
        pix[n] = (oy0 + ty[n]) * Wout + (ox0 + tx[n]);
        mv[n] = mask ? mask[(size_t)b * HWo + pix[n]] : 1.0f;
    }
    #pragma unroll
    for (int m = 0; m < 2; ++m) {
        int cb = co0 + wm * 32 + m * 16 + q * 4;
        float sc[4], sh[4];
        #pragma unroll
        for (int r = 0; r < 4; ++r) { sc[r] = s[cb + r]; sh[r] = t[cb + r]; }
        #pragma unroll
        for (int n = 0; n < 2; ++n) {
            size_t boff = ((size_t)(b * cocn + (cb >> 5)) * HWo + pix[n]) * 32 + (cb & 31);
            float val[4];
            #pragma unroll
            for (int r = 0; r < 4; ++r) val[r] = (acc[m][n][r] * sc[r] + sh[r]) * mv[n];
            if (res) {
                f16x4 rv = *(const f16x4*)&res[boff];
                #pragma unroll
                for (int r = 0; r < 4; ++r) val[r] += (float)rv[r];
            }
            if (relu) {
                #pragma unroll
                for (int r = 0; r < 4; ++r) val[r] = fmaxf(val[r], 0.0f);
            }
            if (out16) {
                f16x4 pk;
                #pragma unroll
                for (int r = 0; r < 4; ++r) pk[r] = (_Float16)val[r];
                *(f16x4*)&out16[boff] = pk;
            }
            if (out32) {
                #pragma unroll
                for (int r = 0; r < 4; ++r)
                    out32[((size_t)b * Cout + cb + r) * HWo + pix[n]] = val[r];
            }
        }
    }
}

// ---------------------------------------------------------------------------
// Barrier-free dense conv (stage4/conv5): wave = 16 pixels x 64 cout.
// ---------------------------------------------------------------------------
__global__ __launch_bounds__(256, 4)
void conv_bf(const _Float16* __restrict__ in, const _Float16* __restrict__ rw,
             const float* __restrict__ s, const float* __restrict__ t,
             const float* __restrict__ mask, const _Float16* __restrict__ res,
             float* __restrict__ out32, _Float16* __restrict__ out16,
             int Cin, int Cout, int Hin, int Win, int Hout, int Wout,
             int stride, int relu)
{
    const int lane = threadIdx.x & 63;
    const int wv = threadIdx.x >> 6;
    const int row = lane & 15, q = lane >> 4;
    const int b = blockIdx.z;
    const int HWo = Hout * Wout;
    const int ntile = HWo >> 4;
    const int gw = blockIdx.x * 4 + wv;
    const int tile = gw % ntile;
    const int cog = gw / ntile;
    const int co0 = cog * 64;
    const int HWin = Hin * Win;
    const int cicn = Cin >> 5;
    const int cocn = Cout >> 5;
    const int nIter = 9 * cicn;

    const int pix = tile * 16 + row;
    const int py = pix / Wout, px_ = pix - py * Wout;
    const int iy0 = py * stride - 1, ix0 = px_ * stride - 1;
    const _Float16* inb = in + (((size_t)b * cicn) * HWin << 5);

    f32x4 acc[4];
    #pragma unroll
    for (int m = 0; m < 4; ++m)
        #pragma unroll
        for (int r = 0; r < 4; ++r) acc[m][r] = 0.0f;

    auto LOADB = [&](int c, f16x8& dst) {
        int tap = c / cicn, cc = c - tap * cicn;
        int iy = iy0 + tap / 3, ix = ix0 + tap - (tap / 3) * 3;
        bool ok = (iy >= 0 && iy < Hin && ix >= 0 && ix < Win);
        dst = ok ? *(const f16x8*)(inb + (((size_t)cc * HWin + (size_t)iy * Win + ix) << 5) + (q << 3))
                 : f16x8{};
    };
    auto LOADA = [&](int c, f16x8 (&dst)[4]) {
        const _Float16* ap = rw + ((size_t)c * Cout + co0 + row) * 32 + (q << 3);
        #pragma unroll
        for (int m = 0; m < 4; ++m) dst[m] = *(const f16x8*)(ap + (size_t)m * 512);
    };

    f16x8 aA[4], aB[4], bfA, bfB;
    LOADB(0, bfA); LOADA(0, aA);
    for (int c = 0; c < nIter; c += 2) {
        bool h1 = (c + 1) < nIter, h2 = (c + 2) < nIter;
        if (h1) { LOADB(c + 1, bfB); LOADA(c + 1, aB); }
        #pragma unroll
        for (int m = 0; m < 4; ++m)
            acc[m] = __builtin_amdgcn_mfma_f32_16x16x32_f16(aA[m], bfA, acc[m], 0, 0, 0);
        if (h2) { LOADB(c + 2, bfA); LOADA(c + 2, aA); }
        if (h1) {
            #pragma unroll
            for (int m = 0; m < 4; ++m)
                acc[m] = __builtin_amdgcn_mfma_f32_16x16x32_f16(aB[m], bfB, acc[m], 0, 0, 0);
        }
    }

    float mv = mask ? mask[(size_t)b * HWo + pix] : 1.0f;
    #pragma unroll
    for (int m = 0; m < 4; ++m) {
        int cb = co0 + m * 16 + q * 4;
        size_t boff = ((size_t)(b * cocn + (cb >> 5)) * HWo + pix) * 32 + (cb & 31);
        float val[4];
        #pragma unroll
        for (int r = 0; r < 4; ++r) val[r] = (acc[m][r] * s[cb + r] + t[cb + r]) * mv;
        if (res) {
            f16x4 rv = *(const f16x4*)&res[boff];
            #pragma unroll
            for (int r = 0; r < 4; ++r) val[r] += (float)rv[r];
        }
        if (relu) {
            #pragma unroll
            for (int r = 0; r < 4; ++r) val[r] = fmaxf(val[r], 0.0f);
        }
        if (out16) {
            f16x4 pk;
            #pragma unroll
            for (int r = 0; r < 4; ++r) pk[r] = (_Float16)val[r];
            *(f16x4*)&out16[boff] = pk;
        }
        if (out32) {
            #pragma unroll
            for (int r = 0; r < 4; ++r)
                out32[((size_t)b * Cout + cb + r) * HWo + pix] = val[r];
        }
    }
}

// ---------------------------------------------------------------------------
// Sparse stage-1 conv, barrier-free: Cin=Cout=32 gathered over active list.
// ---------------------------------------------------------------------------
__global__ __launch_bounds__(256, 4)
void conv_sparse(const _Float16* __restrict__ in, const _Float16* __restrict__ rw,
                 const float* __restrict__ s, const float* __restrict__ t,
                 const int* __restrict__ act, const int* __restrict__ cnt,
                 const _Float16* __restrict__ res,
                 float* __restrict__ out32, _Float16* __restrict__ out16,
                 int Hin, int Win, int relu)
{
    const int tid = threadIdx.x;
    const int lane = tid & 63;
    const int wv = tid >> 6;
    const int row = lane & 15, q = lane >> 4;
    const int b = blockIdx.z;
    const int HW = Hin * Win;
    const int nb = cnt[b];
    const int base = (blockIdx.x * 4 + wv) * 16;
    if (base >= nb) return;

    const int* actb = act + b * HW;
    const _Float16* inb = in + ((size_t)b * HW << 5);

    int j = base + row;
    bool vn = j < nb;
    int pn = vn ? actb[j] : 0;
    int py = pn / Win, px = pn - py * Win;

    f32x4 acc0, acc1;
    #pragma unroll
    for (int r = 0; r < 4; ++r) { acc0[r] = 0.0f; acc1[r] = 0.0f; }

    #pragma unroll
    for (int c = 0; c < 9; ++c) {
        const int dy = c / 3 - 1, dx = c - (c / 3) * 3 - 1;
        f16x8 a0 = *(const f16x8*)(rw + ((size_t)c * 32 + row) * 32 + (q << 3));
        f16x8 a1 = *(const f16x8*)(rw + ((size_t)c * 32 + 16 + row) * 32 + (q << 3));
        int iy = py + dy, ix = px + dx;
        bool ok = vn && iy >= 0 && iy < Hin && ix >= 0 && ix < Win;
        f16x8 bf = ok ? *(const f16x8*)(inb + ((size_t)(iy * Win + ix) << 5) + (q << 3))
                      : f16x8{};
        acc0 = __builtin_amdgcn_mfma_f32_16x16x32_f16(a0, bf, acc0, 0, 0, 0);
        acc1 = __builtin_amdgcn_mfma_f32_16x16x32_f16(a1, bf, acc1, 0, 0, 0);
    }

    if (!vn) return;
    size_t pbase = ((size_t)b * HW + pn) << 5;
    #pragma unroll
    for (int m = 0; m < 2; ++m) {
        const f32x4& am = m ? acc1 : acc0;
        int cb = m * 16 + q * 4;
        float val[4];
        #pragma unroll
        for (int r = 0; r < 4; ++r) val[r] = am[r] * s[cb + r] + t[cb + r];
        if (res) {
            f16x4 rv = *(const f16x4*)&res[pbase + cb];
            #pragma unroll
            for (int r = 0; r < 4; ++r) val[r] += (float)rv[r];
        }
        if (relu) {
            #pragma unroll
            for (int r = 0; r < 4; ++r) val[r] = fmaxf(val[r], 0.0f);
        }
        f16x4 pk;
        #pragma unroll
        for (int r = 0; r < 4; ++r) pk[r] = (_Float16)val[r];
        *(f16x4*)&out16[pbase + cb] = pk;
        if (out32) {
            #pragma unroll
            for (int r = 0; r < 4; ++r)
                out32[((size_t)(b * 32 + cb + r)) * HW + pn] = val[r];
        }
    }
}

extern "C" void kernel_launch(void* const* d_in, const int* in_sizes, int n_in,
                              void* d_out, int out_size, void* d_ws, size_t ws_size,
                              hipStream_t stream) {
    const int B = 2;

    const float* x      = (const float*)d_in[0];
    const float* mask_p = (const float*)d_in[1];
    const float* w1  = (const float*)d_in[2];
    const float* s1  = (const float*)d_in[3];
    const float* t1  = (const float*)d_in[4];
    const float* wd2 = (const float*)d_in[5];
    const float* w2  = (const float*)d_in[6];
    const float* s2  = (const float*)d_in[7];
    const float* t2  = (const float*)d_in[8];
    const float* wd3 = (const float*)d_in[9];
    const float* w3  = (const float*)d_in[10];
    const float* s3  = (const float*)d_in[11];
    const float* t3  = (const float*)d_in[12];
    const float* wd4 = (const float*)d_in[13];
    const float* w4  = (const float*)d_in[14];
    const float* s4  = (const float*)d_in[15];
    const float* t4  = (const float*)d_in[16];
    const float* w5  = (const float*)d_in[17];
    const float* s5  = (const float*)d_in[18];
    const float* t5  = (const float*)d_in[19];

    // d_out slices (fp32 NCHW)
    float* x1o = (float*)d_out;
    float* x2o = x1o + 16777216;
    float* x3o = x2o + 8388608;
    float* x4o = x3o + 4194304;
    float* x5o = x4o + 2097152;

    // workspace
    _Float16* rwbase = (_Float16*)d_ws;        // 5,299,200 halves
    float* m1 = (float*)d_ws + 2649600;
    float* m2 = m1 + 524288;
    float* m3 = m2 + 131072;
    float* m4 = m3 + 32768;
    int* act  = (int*)(m4 + 8192);             // 524288 ints
    int* cnt  = act + 524288;                  // 2 ints (+pad)
    _Float16* P = (_Float16*)(cnt + 32);
    _Float16* Q = P + 16777216;
    _Float16* R = Q + 16777216;

    // ---- fused weight reorder (1 launch, all ck=32) ----
    WArgs wa;
    int cum = 0, si = 0;
    const _Float16* rp[23];
    auto addseg = [&](const float* src, int cin, int cout) {
        wa.seg[si].src = src; wa.seg[si].cin = cin; wa.seg[si].cout = cout;
        wa.seg[si].ck = 32; wa.seg[si].cum = cum;
        rp[si] = rwbase + cum;
        cum += cout * cin * 9; si++;
    };
    for (int i = 0; i < 5; ++i) addseg(w1 + (size_t)i * 9216, 32, 32);
    addseg(wd2, 32, 64);
    for (int i = 0; i < 4; ++i) addseg(w2 + (size_t)i * 36864, 64, 64);
    addseg(wd3, 64, 128);
    for (int i = 0; i < 4; ++i) addseg(w3 + (size_t)i * 147456, 128, 128);
    addseg(wd4, 128, 256);
    for (int i = 0; i < 4; ++i) addseg(w4 + (size_t)i * 589824, 256, 256);
    for (int i = 0; i < 3; ++i) addseg(w5 + (size_t)i * 589824, 256, 256);
    wa.total = cum;  // 5,299,200
    reorder_all<<<(cum + 255) / 256, 256, 0, stream>>>(wa, rwbase);

    // ---- zero-init sparse-written buffers + counters ----
    hipMemsetAsync(cnt, 0, 2 * sizeof(int), stream);
    hipMemsetAsync(Q, 0, 2 * 16777216 * sizeof(_Float16), stream);  // Q + R adjacent
    hipMemsetAsync(x1o, 0, 16777216 * sizeof(float), stream);

    // ---- masks + x0 + fused compaction ----
    {
        int n = B * 512 * 512;
        mask_make<<<(n + 255) / 256, 256, 0, stream>>>(x, mask_p, m1, P, act, cnt, B, 512 * 512);
        mask_down<<<(B * 256 * 256 + 255) / 256, 256, 0, stream>>>(m1, m2, B, 512, 512, 256, 256);
        mask_down<<<(B * 128 * 128 + 255) / 256, 256, 0, stream>>>(m2, m3, B, 256, 256, 128, 128);
        mask_down<<<(B * 64 * 64 + 255) / 256, 256, 0, stream>>>(m3, m4, B, 128, 128, 64, 64);
    }

    auto conv = [&](const _Float16* in, const _Float16* rwp, const float* sp, const float* tp,
                    const float* mk, const _Float16* rs, float* o32, _Float16* o16,
                    int Cin, int Cout, int Hin, int Win, int stride) {
        int Hout = Hin / stride, Wout = Win / stride, HWo = Hout * Wout;
        int TW = (Wout < 64) ? Wout : 64;
        int TH = 64 / TW;
        dim3 grid(HWo / 64, Cout / 64, B);
        conv_mfma<64, 64, 32><<<grid, 256, 0, stream>>>(in, rwp, sp, tp, mk, rs, o32, o16,
            Cin, Cout, Hin, Win, Hout, Wout, TH, TW, stride, 1);
    };
    auto hconv = [&](const _Float16* in, const _Float16* rwp, const float* sp, const float* tp,
                     const float* mk, const _Float16* rs, float* o32, _Float16* o16,
                     int Cin, int Cout, int Hin, int Win) {
        dim3 grid((Hin / 8) * (Win / 8), Cout / 64, B);
        if (Cin == 64)
            conv_halo<64><<<grid, 256, 0, stream>>>(in, rwp, sp, tp, mk, rs, o32, o16,
                Cout, Hin, Win, 1);
        else
            conv_halo<128><<<grid, 256, 0, stream>>>(in, rwp, sp, tp, mk, rs, o32, o16,
                Cout, Hin, Win, 1);
    };
    auto bconv = [&](const _Float16* in, const _Float16* rwp, const float* sp, const float* tp,
                     const float* mk, const _Float16* rs, float* o32, _Float16* o16,
                     int Cin, int Cout, int Hin, int Win, int stride) {
        int Hout = Hin / stride, Wout = Win / stride, HWo = Hout * Wout;
        int waves = (HWo / 16) * (Cout / 64);
        dim3 grid(waves / 4, 1, B);
        conv_bf<<<grid, 256, 0, stream>>>(in, rwp, sp, tp, mk, rs, o32, o16,
            Cin, Cout, Hin, Win, Hout, Wout, stride, 1);
    };
    auto sconv = [&](const _Float16* in, const _Float16* rwp, const float* sp, const float* tp,
                     const _Float16* rs, float* o32, _Float16* o16) {
        dim3 grid(1024, 1, B);
        conv_sparse<<<grid, 256, 0, stream>>>(in, rwp, sp, tp, act, cnt, rs, o32, o16, 512, 512, 1);
    };

    // ---- stage 1 (32ch, 512x512) sparse: P=x0 ----
    sconv(P, rp[0], s1 + 0,   t1 + 0,   nullptr, nullptr, Q);
    sconv(Q, rp[1], s1 + 32,  t1 + 32,  nullptr, nullptr, R);
    sconv(R, rp[2], s1 + 64,  t1 + 64,  Q,       nullptr, P);   // P inactive sites = 0 from x0
    sconv(P, rp[3], s1 + 96,  t1 + 96,  nullptr, nullptr, Q);
    sconv(Q, rp[4], s1 + 128, t1 + 128, P,       x1o,     R);   // x1 = R

    // ---- stage 2 (32->64, 512->256): in R ----
    conv (R, rp[5], s2 + 0,   t2 + 0,   m2, nullptr, nullptr, P, 32, 64, 512, 512, 2);
    hconv(P, rp[6], s2 + 64,  t2 + 64,  m2, nullptr, nullptr, Q, 64, 64, 256, 256);
    hconv(Q, rp[7], s2 + 128, t2 + 128, m2, P,       nullptr, P, 64, 64, 256, 256);
    hconv(P, rp[8], s2 + 192, t2 + 192, m2, nullptr, nullptr, Q, 64, 64, 256, 256);
    hconv(Q, rp[9], s2 + 256, t2 + 256, m2, P,       x2o,     P, 64, 64, 256, 256);

    // ---- stage 3 (64->128, 256->128): x2 = P ----
    conv (P, rp[10], s3 + 0,   t3 + 0,   m3, nullptr, nullptr, Q, 64, 128, 256, 256, 2);
    hconv(Q, rp[11], s3 + 128, t3 + 128, m3, nullptr, nullptr, R, 128, 128, 128, 128);
    hconv(R, rp[12], s3 + 256, t3 + 256, m3, Q,       nullptr, Q, 128, 128, 128, 128);
    hconv(Q, rp[13], s3 + 384, t3 + 384, m3, nullptr, nullptr, R, 128, 128, 128, 128);
    hconv(R, rp[14], s3 + 512, t3 + 512, m3, Q,       x3o,     Q, 128, 128, 128, 128);

    // ---- stage 4 (128->256, 128->64): x3 = Q, barrier-free ----
    bconv(Q, rp[15], s4 + 0,    t4 + 0,    m4, nullptr, nullptr, P, 128, 256, 128, 128, 2);
    bconv(P, rp[16], s4 + 256,  t4 + 256,  m4, nullptr, nullptr, R, 256, 256, 64, 64, 1);
    bconv(R, rp[17], s4 + 512,  t4 + 512,  m4, P,       nullptr, P, 256, 256, 64, 64, 1);
    bconv(P, rp[18], s4 + 768,  t4 + 768,  m4, nullptr, nullptr, R, 256, 256, 64, 64, 1);
    bconv(R, rp[19], s4 + 1024, t4 + 1024, m4, P,       x4o,     P, 256, 256, 64, 64, 1);

    // ---- conv5 (dense): x4 = P, barrier-free ----
    bconv(P, rp[20], s5 + 0,   t5 + 0,   nullptr, nullptr, nullptr, Q, 256, 256, 64, 64, 2);
    bconv(Q, rp[21], s5 + 256, t5 + 256, nullptr, nullptr, nullptr, R, 256, 256, 32, 32, 1);
    bconv(R, rp[22], s5 + 512, t5 + 512, nullptr, nullptr, x5o, nullptr, 256, 256, 32, 32, 1);
}